// Round 2
// baseline (329.360 us; speedup 1.0000x reference)
//
#include <hip/hip_runtime.h>
#include <hip/hip_bf16.h>

#define EMBED 64
#define DEG 32

__global__ __launch_bounds__(256) void interagg_kernel(
    const float* __restrict__ features,   // (1e6, 64) fp32
    const float* __restrict__ alpha,      // (128, 3) fp32
    const int* __restrict__ nodes,        // (N,)
    const int* __restrict__ ni1,          // (N, 32)
    const int* __restrict__ ni2,
    const int* __restrict__ ni3,
    float* __restrict__ out)              // (N, 192) fp32
{
    __shared__ float s_self[EMBED];
    __shared__ float s_w[3][EMBED];    // softmax(alpha) rows 64..127
    __shared__ float s_agg[3][EMBED];  // relu(mean_r)

    const int n    = blockIdx.x;
    const int tid  = threadIdx.x;
    const int wave = tid >> 6;
    const int lane = tid & 63;

    if (wave < 3) {
        // --- relation aggregation: mean over 32 neighbor rows of 64 fp32 ---
        const int* nb = ((wave == 0) ? ni1 : (wave == 1) ? ni2 : ni3) + n * DEG;
        const int g   = lane >> 4;   // group 0..3 (16 lanes each)
        const int sub = lane & 15;   // float4 chunk within the 256B row

        // this group's 8 neighbors: g, g+4, ..., g+28
        int idx[8];
        #pragma unroll
        for (int k = 0; k < 8; k++) idx[k] = nb[g + 4 * k];

        const float4* f4 = (const float4*)features;  // 16 float4 per row
        float acc0 = 0.f, acc1 = 0.f, acc2 = 0.f, acc3 = 0.f;
        #pragma unroll
        for (int k = 0; k < 8; k++) {
            float4 v = f4[(size_t)idx[k] * 16 + sub];
            acc0 += v.x; acc1 += v.y; acc2 += v.z; acc3 += v.w;
        }

        // reduce the 4 groups (lane strides 16, 32)
        #pragma unroll
        for (int off = 16; off < 64; off <<= 1) {
            acc0 += __shfl_xor(acc0, off, 64);
            acc1 += __shfl_xor(acc1, off, 64);
            acc2 += __shfl_xor(acc2, off, 64);
            acc3 += __shfl_xor(acc3, off, 64);
        }

        if (g == 0) {
            float m0 = acc0 * (1.0f / DEG);
            float m1 = acc1 * (1.0f / DEG);
            float m2 = acc2 * (1.0f / DEG);
            float m3 = acc3 * (1.0f / DEG);
            s_agg[wave][sub * 4 + 0] = m0 > 0.f ? m0 : 0.f;
            s_agg[wave][sub * 4 + 1] = m1 > 0.f ? m1 : 0.f;
            s_agg[wave][sub * 4 + 2] = m2 > 0.f ? m2 : 0.f;
            s_agg[wave][sub * 4 + 3] = m3 > 0.f ? m3 : 0.f;
        }
    } else {
        // --- wave 3: self features + softmax(alpha) rows 64..127 ---
        const int node = nodes[n];
        s_self[lane] = features[(size_t)node * EMBED + lane];

        const int row = 64 + lane;
        float a0 = alpha[row * 3 + 0];
        float a1 = alpha[row * 3 + 1];
        float a2 = alpha[row * 3 + 2];
        float mx = fmaxf(a0, fmaxf(a1, a2));
        float e0 = expf(a0 - mx), e1 = expf(a1 - mx), e2 = expf(a2 - mx);
        float inv = 1.0f / (e0 + e1 + e2);
        s_w[0][lane] = e0 * inv;
        s_w[1][lane] = e1 * inv;
        s_w[2][lane] = e2 * inv;
    }

    __syncthreads();

    // --- epilogue: out[n, 0:64]=self, [64:128]=relu(self) (softmax rows sum
    //     to 1, relu(self) is relation-invariant), [128:192]=sum_r w*agg ---
    const size_t base = (size_t)n * 192;
    if (tid < 64) {
        out[base + tid] = s_self[tid];
    } else if (tid < 128) {
        const int j = tid - 64;
        float v = s_self[j];
        out[base + tid] = v > 0.f ? v : 0.f;
    } else if (tid < 192) {
        const int j = tid - 128;
        out[base + tid] = s_agg[0][j] * s_w[0][j]
                        + s_agg[1][j] * s_w[1][j]
                        + s_agg[2][j] * s_w[2][j];
    }
}

extern "C" void kernel_launch(void* const* d_in, const int* in_sizes, int n_in,
                              void* d_out, int out_size, void* d_ws, size_t ws_size,
                              hipStream_t stream) {
    const float* features = (const float*)d_in[0];
    const float* alpha    = (const float*)d_in[1];
    const int* nodes      = (const int*)d_in[2];
    const int* ni1        = (const int*)d_in[3];
    const int* ni2        = (const int*)d_in[4];
    const int* ni3        = (const int*)d_in[5];
    float* out            = (float*)d_out;

    const int nbatch = in_sizes[2];  // 8192
    interagg_kernel<<<nbatch, 256, 0, stream>>>(
        features, alpha, nodes, ni1, ni2, ni3, out);
}

// Round 3
// 328.320 us; speedup vs baseline: 1.0032x; 1.0032x over previous
//
#include <hip/hip_runtime.h>

#define EMBED 64
#define DEG 32

// One wave (64 lanes) per batch node: all 3 relations + self + epilogue.
// 24 independent float4 gathers in flight per wave; no LDS, no barrier.
__global__ __launch_bounds__(256) void interagg_kernel(
    const float* __restrict__ features,   // (1e6, 64) fp32
    const float* __restrict__ alpha,      // (128, 3) fp32
    const int* __restrict__ nodes,        // (N,)
    const int* __restrict__ ni1,          // (N, 32)
    const int* __restrict__ ni2,
    const int* __restrict__ ni3,
    float* __restrict__ out,              // (N, 192) fp32
    int nbatch)
{
    const int tid  = threadIdx.x;
    const int wave = tid >> 6;
    const int lane = tid & 63;
    const int n    = blockIdx.x * 4 + wave;
    if (n >= nbatch) return;

    const int g   = lane >> 4;   // group 0..3: which row of the 4-in-flight
    const int sub = lane & 15;   // float4 chunk within the 256B row

    const int* nb0 = ni1 + (size_t)n * DEG;
    const int* nb1 = ni2 + (size_t)n * DEG;
    const int* nb2 = ni3 + (size_t)n * DEG;
    const float4* f4 = (const float4*)features;  // 16 float4 per row

    // ---- load all 96 indices up front (broadcast within 16-lane groups) ----
    int idx[3][8];
    #pragma unroll
    for (int k = 0; k < 8; k++) {
        idx[0][k] = nb0[g + 4 * k];
        idx[1][k] = nb1[g + 4 * k];
        idx[2][k] = nb2[g + 4 * k];
    }

    // self row (coalesced, 1 float per lane) + alpha rows 64..127, early issue
    const int node = nodes[n];
    const float self_v = features[(size_t)node * EMBED + lane];
    const int arow = 64 + lane;
    const float a0 = alpha[arow * 3 + 0];
    const float a1 = alpha[arow * 3 + 1];
    const float a2 = alpha[arow * 3 + 2];

    // ---- 24 independent gathers: sum over 32 neighbors per relation ----
    float acc[3][4];
    #pragma unroll
    for (int r = 0; r < 3; r++)
        #pragma unroll
        for (int e = 0; e < 4; e++) acc[r][e] = 0.f;

    #pragma unroll
    for (int r = 0; r < 3; r++) {
        #pragma unroll
        for (int k = 0; k < 8; k++) {
            float4 v = f4[(size_t)idx[r][k] * 16 + sub];
            acc[r][0] += v.x; acc[r][1] += v.y;
            acc[r][2] += v.z; acc[r][3] += v.w;
        }
    }

    // ---- reduce the 4 groups (lanes strided 16, 32) ----
    #pragma unroll
    for (int r = 0; r < 3; r++)
        #pragma unroll
        for (int e = 0; e < 4; e++) {
            acc[r][e] += __shfl_xor(acc[r][e], 16, 64);
            acc[r][e] += __shfl_xor(acc[r][e], 32, 64);
        }

    // ---- transpose to 1 column/lane: lane L wants column L = 4*(L>>2)+(L&3),
    //      held by any lane with sub == L>>2 (component L&3) ----
    const int src   = lane >> 2;
    const int e_sel = lane & 3;
    float relagg[3];
    #pragma unroll
    for (int r = 0; r < 3; r++) {
        float t0 = __shfl(acc[r][0], src, 64);
        float t1 = __shfl(acc[r][1], src, 64);
        float t2 = __shfl(acc[r][2], src, 64);
        float t3 = __shfl(acc[r][3], src, 64);
        float t  = (e_sel == 0) ? t0 : (e_sel == 1) ? t1 : (e_sel == 2) ? t2 : t3;
        t *= (1.0f / DEG);
        relagg[r] = t > 0.f ? t : 0.f;
    }

    // ---- per-feature softmax over the 3 relations (alpha rows 64..127) ----
    const float mx  = fmaxf(a0, fmaxf(a1, a2));
    const float e0  = __expf(a0 - mx), e1 = __expf(a1 - mx), e2 = __expf(a2 - mx);
    const float inv = 1.0f / (e0 + e1 + e2);

    // ---- epilogue: [0:64]=self, [64:128]=relu(self) (softmax rows sum to 1,
    //      relu(self) is relation-invariant), [128:192]=weighted agg ----
    const size_t base = (size_t)n * 192;
    out[base + lane] = self_v;
    out[base + 64 + lane] = self_v > 0.f ? self_v : 0.f;
    out[base + 128 + lane] =
        (relagg[0] * e0 + relagg[1] * e1 + relagg[2] * e2) * inv;
}

extern "C" void kernel_launch(void* const* d_in, const int* in_sizes, int n_in,
                              void* d_out, int out_size, void* d_ws, size_t ws_size,
                              hipStream_t stream) {
    const float* features = (const float*)d_in[0];
    const float* alpha    = (const float*)d_in[1];
    const int* nodes      = (const int*)d_in[2];
    const int* ni1        = (const int*)d_in[3];
    const int* ni2        = (const int*)d_in[4];
    const int* ni3        = (const int*)d_in[5];
    float* out            = (float*)d_out;

    const int nbatch = in_sizes[2];  // 8192
    const int blocks = (nbatch + 3) / 4;  // 4 waves per block, 1 node per wave
    interagg_kernel<<<blocks, 256, 0, stream>>>(
        features, alpha, nodes, ni1, ni2, ni3, out, nbatch);
}